// Round 13
// baseline (366.312 us; speedup 1.0000x reference)
//
#include <hip/hip_runtime.h>
#include <math.h>

// Problem constants
#define HW   16384        // 128*128
#define CC   256
#define cC   64
#define BB   16
#define CHW  (CC*HW)      // 4194304
#define cHW  (cC*HW)      // 1048576

// ws float offsets (ws_size = 1 GiB)
#define WS_TB    0                      // t bf16
#define WS_H1B   8388608                // h1 bf16
#define WS_W2E   50331648
#define WS_K1E   (WS_W2E + 5184)
#define WS_GN1A  (WS_K1E + 16)
#define WS_GNSA  (WS_GN1A + 512)
#define WS_GN2A  (WS_GNSA + 512)
#define WS_W1P   (WS_GN2A + 512)
#define WS_W2P   (WS_W1P + 8192)

typedef __attribute__((ext_vector_type(8))) short bf16x8;
typedef __attribute__((ext_vector_type(4))) float f32x4;

__device__ inline unsigned short f2bf(float f) {
    union { float f; unsigned u; } c; c.f = f;
    unsigned r = c.u + 0x7FFFu + ((c.u >> 16) & 1u);
    return (unsigned short)(r >> 16);
}
__device__ inline float bf2f(unsigned short h) {
    union { unsigned u; float f; } c; c.u = ((unsigned)h) << 16; return c.f;
}

// ---------------------------------------------------------------------------
// K0: effective kernels; zero GN accum; pack conv weights into MFMA frag order
// ---------------------------------------------------------------------------
__global__ void k_setup(const float* __restrict__ W1, const float* __restrict__ W2,
                        const float* __restrict__ c1w, const float* __restrict__ c2w,
                        float* __restrict__ k1e, float* __restrict__ w2e,
                        float* __restrict__ accz, unsigned short* __restrict__ w1p,
                        unsigned short* __restrict__ w2p) {
    __shared__ float tapsum[81];
    __shared__ float a2s[4];
    int tdx = threadIdx.x;
    for (int i = tdx; i < 1536; i += 128) accz[i] = 0.f;
    for (int e = tdx; e < 16384; e += 128) {
        int fi = e >> 9, rem = e & 511;
        int l = rem >> 3, j = rem & 7;
        int ks = fi >> 2, nf = fi & 3;
        int c = ks * 32 + (l >> 4) * 8 + j;
        int oc = nf * 16 + (l & 15);
        w1p[e] = f2bf(c1w[oc * 256 + c]);
    }
    for (int e = tdx; e < 16384; e += 128) {
        int fi = e >> 9, rem = e & 511;
        int l = rem >> 3, j = rem & 7;
        int ks = fi >> 4, nfg = fi & 15;
        int c = ks * 32 + (l >> 4) * 8 + j;
        int oc = nfg * 16 + (l & 15);
        w2p[e] = f2bf(c2w[oc * 64 + c]);
    }
    if (tdx < 81) {
        float s = 0.f;
        for (int ch = 0; ch < 64; ++ch) s += W2[ch * 81 + tdx];
        tapsum[tdx] = s;
    }
    __syncthreads();
    if (tdx == 0) {
        float ring[4] = {0.f, 0.f, 0.f, 0.f};
        for (int i = 0; i < 9; ++i)
            for (int j = 0; j < 9; ++j) {
                int d = max(abs(i - 4), abs(j - 4));
                int r = (d <= 1) ? 0 : (d - 1);
                ring[r] += tapsum[i * 9 + j];
            }
        float den2[4] = {576.f, 1024.f, 1536.f, 2048.f};
        float v[4], mx = -1e30f;
        for (int p = 0; p < 4; ++p) { v[p] = ring[p] / den2[p]; mx = fmaxf(mx, v[p]); }
        float se = 0.f;
        for (int p = 0; p < 4; ++p) { v[p] = expf(v[p] - mx); se += v[p]; }
        for (int p = 0; p < 4; ++p) a2s[p] = v[p] / se;
        float k1[9];
        for (int k = 0; k < 9; ++k) k1[k] = W1[k];
        float num[4];
        num[0] = k1[3] + k1[4] + k1[5];
        num[1] = k1[2] + k1[6];
        num[2] = k1[1] + k1[7];
        num[3] = k1[0] + k1[8];
        float den1[4] = {3.f, 2.f, 2.f, 2.f};
        mx = -1e30f;
        for (int p = 0; p < 4; ++p) { v[p] = num[p] / den1[p]; mx = fmaxf(mx, v[p]); }
        se = 0.f;
        for (int p = 0; p < 4; ++p) { v[p] = expf(v[p] - mx); se += v[p]; }
        float a1[4];
        for (int p = 0; p < 4; ++p) a1[p] = v[p] / se;
        float s1arr[5];
        s1arr[0] = 1.f; s1arr[1] = 1.f;
        s1arr[4] = a1[3]; s1arr[3] = a1[2] + a1[3]; s1arr[2] = a1[1] + s1arr[3];
        for (int k = 0; k < 9; ++k) { int d = abs(k - 4); k1e[k] = k1[k] * s1arr[d]; }
    }
    __syncthreads();
    float s2arr[5];
    s2arr[0] = 1.f; s2arr[1] = 1.f;
    s2arr[4] = a2s[3]; s2arr[3] = a2s[2] + a2s[3]; s2arr[2] = a2s[1] + s2arr[3];
    for (int idx = tdx; idx < 64 * 81; idx += 128) {
        int tap = idx % 81;
        int i = tap / 9, j = tap - i * 9;
        int d = max(abs(i - 4), abs(j - 4));
        w2e[idx] = W2[idx] * s2arr[d];
    }
}

// ---------------------------------------------------------------------------
// GN affine helper: from accum pair -> scale/shift for channel ch
// ---------------------------------------------------------------------------
__device__ inline void gn_affine(const float* __restrict__ acc, int b, int g,
                                 float inv_n, const float* __restrict__ gw,
                                 const float* __restrict__ gb, int ch,
                                 float& sc, float& sh) {
    float s = acc[(b * 16 + g) * 2], ss = acc[(b * 16 + g) * 2 + 1];
    float mu = s * inv_n;
    float var = ss * inv_n - mu * mu;
    float rstd = rsqrtf(var + 1e-5f);
    sc = gw[ch] * rstd;
    sh = gb[ch] - mu * sc;
}

// ---------------------------------------------------------------------------
// K1: conv1 (1x1, 256->64) via bf16 MFMA -> h1 bf16 [ch][p] ; GN1 sums
// ---------------------------------------------------------------------------
__global__ __launch_bounds__(256) void k_conv1(const float* __restrict__ x,
        const unsigned short* __restrict__ w1p, const float* __restrict__ b1,
        unsigned short* __restrict__ h1, float* __restrict__ gn1a) {
    int bid = blockIdx.x;
    int b = bid >> 6, pt = bid & 63;
    int tid = threadIdx.x;
    int w = tid >> 6, lane = tid & 63;
    int l15 = lane & 15, lg = lane >> 4;
    int p_wave = pt * 256 + w * 64;
    const bf16x8* w1v = (const bf16x8*)w1p;
    f32x4 acc[4][4];
#pragma unroll
    for (int mf = 0; mf < 4; ++mf)
#pragma unroll
        for (int nf = 0; nf < 4; ++nf) acc[mf][nf] = (f32x4){0.f, 0.f, 0.f, 0.f};
    const float* xb = x + b * CHW;
#pragma unroll 1
    for (int ks = 0; ks < 8; ++ks) {
        int c0 = ks * 32 + lg * 8;
        bf16x8 afr[4];
#pragma unroll
        for (int mf = 0; mf < 4; ++mf) {
            const float* xp = xb + c0 * HW + p_wave + mf * 16 + l15;
            bf16x8 a;
#pragma unroll
            for (int j = 0; j < 8; ++j) a[j] = (short)f2bf(__builtin_nontemporal_load(xp + j * HW));
            afr[mf] = a;
        }
#pragma unroll
        for (int nf = 0; nf < 4; ++nf) {
            bf16x8 bfr = w1v[(ks * 4 + nf) * 64 + lane];
#pragma unroll
            for (int mf = 0; mf < 4; ++mf)
                acc[mf][nf] = __builtin_amdgcn_mfma_f32_16x16x32_bf16(afr[mf], bfr, acc[mf][nf], 0, 0, 0);
        }
    }
    __shared__ float red[4][16][2];
    unsigned short* hb = h1 + b * cHW;
#pragma unroll
    for (int nf = 0; nf < 4; ++nf) {
        int oc = nf * 16 + l15;
        float bias = b1[oc];
        float s = 0.f, ss = 0.f;
#pragma unroll
        for (int mf = 0; mf < 4; ++mf) {
            f32x4 v = acc[mf][nf];
            v[0] += bias; v[1] += bias; v[2] += bias; v[3] += bias;
            ushort4 hv = make_ushort4(f2bf(v[0]), f2bf(v[1]), f2bf(v[2]), f2bf(v[3]));
            *(ushort4*)(hb + oc * HW + p_wave + mf * 16 + lg * 4) = hv;
            s += v[0] + v[1] + v[2] + v[3];
            ss += v[0] * v[0] + v[1] * v[1] + v[2] * v[2] + v[3] * v[3];
        }
        s += __shfl_xor(s, 16, 64); ss += __shfl_xor(ss, 16, 64);
        s += __shfl_xor(s, 32, 64); ss += __shfl_xor(ss, 32, 64);
        s += __shfl_xor(s, 1, 64);  ss += __shfl_xor(ss, 1, 64);
        s += __shfl_xor(s, 2, 64);  ss += __shfl_xor(ss, 2, 64);
        if (lg == 0 && (l15 & 3) == 0) {
            int g = nf * 4 + (l15 >> 2);
            red[w][g][0] = s; red[w][g][1] = ss;
        }
    }
    __syncthreads();
    if (tid < 32) {
        int g = tid >> 1, c = tid & 1;
        float v = red[0][g][c] + red[1][g][c] + red[2][g][c] + red[3][g][c];
        atomicAdd(&gn1a[(b * 16 + g) * 2 + c], v);
    }
}

// ---------------------------------------------------------------------------
// K3: channel-dim 9-tap conv (pad 4) -> t (bf16) ; 2 positions/thread ;
//     GN1 affine computed inline from gn1a
// ---------------------------------------------------------------------------
__global__ __launch_bounds__(256) void k_x3(const unsigned short* __restrict__ h1,
        const float* __restrict__ gn1a, const float* __restrict__ g1w,
        const float* __restrict__ g1b, const float* __restrict__ k1e,
        unsigned short* __restrict__ t) {
    int i = blockIdx.x * 256 + threadIdx.x;     // 0..131071
    int b = i >> 13, p = (i & 8191) * 2;
    __shared__ float lsc[64], lsh[64], lke[9];
    if (threadIdx.x < 64) {
        int ch = threadIdx.x;
        float sc, sh;
        gn_affine(gn1a, b, ch >> 2, 1.f / 65536.f, g1w, g1b, ch, sc, sh);
        lsc[ch] = sc; lsh[ch] = sh;
    }
    if (threadIdx.x < 9) lke[threadIdx.x] = k1e[threadIdx.x];
    __syncthreads();
    const unsigned short* hb = h1 + b * cHW + p;
    float2 win[9];
#pragma unroll
    for (int k = 0; k < 9; ++k) {
        int ch = k - 4;
        if (ch >= 0) {
            ushort2 hv = *(const ushort2*)(hb + ch * HW);
            float s = lsc[ch], h = lsh[ch];
            win[k] = make_float2(fmaf(bf2f(hv.x), s, h), fmaf(bf2f(hv.y), s, h));
        } else win[k] = make_float2(0.f, 0.f);
    }
    unsigned short* tb = t + b * cHW + p;
#pragma unroll
    for (int ch = 0; ch < 64; ++ch) {
        float2 s = make_float2(0.f, 0.f);
#pragma unroll
        for (int k = 0; k < 9; ++k) {
            float kv = lke[k];
            s.x = fmaf(win[k].x, kv, s.x);
            s.y = fmaf(win[k].y, kv, s.y);
        }
        *(ushort2*)(tb + ch * HW) = make_ushort2(f2bf(s.x), f2bf(s.y));
#pragma unroll
        for (int k = 0; k < 8; ++k) win[k] = win[k + 1];
        int nc = ch + 5;
        if (nc < 64) {
            ushort2 hv = *(const ushort2*)(hb + nc * HW);
            float sN = lsc[nc], hN = lsh[nc];
            win[8] = make_float2(fmaf(bf2f(hv.x), sN, hN), fmaf(bf2f(hv.y), sN, hN));
        } else win[8] = make_float2(0.f, 0.f);
    }
}

// ---------------------------------------------------------------------------
// K4: depthwise 9x9 spatial conv ; t += x_sa (bf16 RMW) ; GN_s sums ;
//     GN1 affine (single channel) computed inline
// ---------------------------------------------------------------------------
__global__ __launch_bounds__(256) void k_xsa(const unsigned short* __restrict__ h1,
        const float* __restrict__ gn1a, const float* __restrict__ g1w,
        const float* __restrict__ g1b, const float* __restrict__ w2e,
        unsigned short* __restrict__ t, float* __restrict__ gnsa) {
    int bid = blockIdx.x;
    int b = bid >> 8, ch = (bid >> 2) & 63, rt = bid & 3;
    int r0 = rt * 32;
    int tid = threadIdx.x;
    float sc, sh;
    gn_affine(gn1a, b, ch >> 2, 1.f / 65536.f, g1w, g1b, ch, sc, sh);
    const unsigned short* hp = h1 + b * cHW + ch * HW;
    __shared__ float tile[40 * 136];            // 21.25 KB
    for (int li = tid; li < 40 * 34; li += 256) {
        int row = li / 34, c4 = li - row * 34;
        int col = c4 * 4;
        int gr = r0 - 4 + row;
        float4 z = make_float4(0.f, 0.f, 0.f, 0.f);
        if (gr >= 0 && gr < 128 && c4 >= 1 && c4 <= 32) {
            int gc = col - 4;
            ushort4 hv = *(const ushort4*)(hp + gr * 128 + gc);
            z = make_float4(fmaf(bf2f(hv.x), sc, sh), fmaf(bf2f(hv.y), sc, sh),
                            fmaf(bf2f(hv.z), sc, sh), fmaf(bf2f(hv.w), sc, sh));
        }
        *(float4*)&tile[row * 136 + col] = z;
    }
    __syncthreads();
    int r4g = tid >> 5, c4g = tid & 31;
    int orow0 = r4g * 4, oc0 = c4g * 4;
    const float* wch = w2e + ch * 81;
    float acc[4][4];
#pragma unroll
    for (int r = 0; r < 4; ++r)
#pragma unroll
        for (int k = 0; k < 4; ++k) acc[r][k] = 0.f;
#pragma unroll
    for (int d = 0; d < 12; ++d) {
        const float* lr = &tile[(orow0 + d) * 136 + oc0];
        float v[12];
        *(float4*)&v[0] = *(const float4*)lr;
        *(float4*)&v[4] = *(const float4*)(lr + 4);
        *(float4*)&v[8] = *(const float4*)(lr + 8);
#pragma unroll
        for (int r = 0; r < 4; ++r) {
            if (r <= d && d - r <= 8) {
                const int i = d - r;
#pragma unroll
                for (int j = 0; j < 9; ++j) {
                    float wv = wch[i * 9 + j];
                    acc[r][0] = fmaf(v[j + 0], wv, acc[r][0]);
                    acc[r][1] = fmaf(v[j + 1], wv, acc[r][1]);
                    acc[r][2] = fmaf(v[j + 2], wv, acc[r][2]);
                    acc[r][3] = fmaf(v[j + 3], wv, acc[r][3]);
                }
            }
        }
    }
    float s = 0.f, ss = 0.f;
    unsigned short* tpb = t + b * cHW + ch * HW + (r0 + orow0) * 128 + oc0;
#pragma unroll
    for (int r = 0; r < 4; ++r) {
        unsigned short* tp = tpb + r * 128;
        ushort4 tv = *(const ushort4*)tp;
        float r0v = bf2f(tv.x) + acc[r][0];
        float r1v = bf2f(tv.y) + acc[r][1];
        float r2v = bf2f(tv.z) + acc[r][2];
        float r3v = bf2f(tv.w) + acc[r][3];
        *(ushort4*)tp = make_ushort4(f2bf(r0v), f2bf(r1v), f2bf(r2v), f2bf(r3v));
        s += r0v + r1v + r2v + r3v;
        ss += r0v * r0v + r1v * r1v + r2v * r2v + r3v * r3v;
    }
#pragma unroll
    for (int off = 32; off; off >>= 1) { s += __shfl_xor(s, off, 64); ss += __shfl_xor(ss, off, 64); }
    __shared__ float rs[4], rss[4];
    int lane = tid & 63, wv2 = tid >> 6;
    if (lane == 0) { rs[wv2] = s; rss[wv2] = ss; }
    __syncthreads();
    if (tid == 0) {
        int gi = (b * 16 + (ch >> 2)) * 2;
        atomicAdd(&gnsa[gi], rs[0] + rs[1] + rs[2] + rs[3]);
        atomicAdd(&gnsa[gi + 1], rss[0] + rss[1] + rss[2] + rss[3]);
    }
}

#define ROWU 68   // padded u16 row stride for the 64-pos LDS panel

// ---------------------------------------------------------------------------
// Shared staging+GEMM body for conv2 (used by stats pass and fused final).
// Stages normalized+relu'd t panel (64ch x 64pos bf16) in LDS; computes the
// wave's 64oc x 64pos quadrant into acc.
// ---------------------------------------------------------------------------
__device__ inline void conv2_panel(const unsigned short* __restrict__ t,
        const float* __restrict__ gnsa, const float* __restrict__ gsw,
        const float* __restrict__ gsb, const unsigned short* __restrict__ w2p,
        int b, int p0, int tid, int w, int lane, int l15, int lg,
        float* lsc, float* lsh, unsigned short* tps, f32x4 (&acc)[4][4]) {
    if (tid < 64) {
        float sc, sh;
        gn_affine(gnsa, b, tid >> 2, 1.f / 65536.f, gsw, gsb, tid, sc, sh);
        lsc[tid] = sc; lsh[tid] = sh;
    }
    __syncthreads();
    {
        int ch = tid >> 2, c8 = tid & 3;
        float sc = lsc[ch], sh = lsh[ch];
        const unsigned short* tg = t + b * cHW + ch * HW + p0;
#pragma unroll
        for (int half = 0; half < 2; ++half) {
            int off = (c8 + half * 4) * 8;
            ushort4 a0 = *(const ushort4*)(tg + off);
            ushort4 a1 = *(const ushort4*)(tg + off + 4);
            ushort4 o0, o1;
            o0.x = f2bf(fmaxf(fmaf(bf2f(a0.x), sc, sh), 0.f));
            o0.y = f2bf(fmaxf(fmaf(bf2f(a0.y), sc, sh), 0.f));
            o0.z = f2bf(fmaxf(fmaf(bf2f(a0.z), sc, sh), 0.f));
            o0.w = f2bf(fmaxf(fmaf(bf2f(a0.w), sc, sh), 0.f));
            o1.x = f2bf(fmaxf(fmaf(bf2f(a1.x), sc, sh), 0.f));
            o1.y = f2bf(fmaxf(fmaf(bf2f(a1.y), sc, sh), 0.f));
            o1.z = f2bf(fmaxf(fmaf(bf2f(a1.z), sc, sh), 0.f));
            o1.w = f2bf(fmaxf(fmaf(bf2f(a1.w), sc, sh), 0.f));
            *(ushort4*)(&tps[ch * ROWU + off]) = o0;
            *(ushort4*)(&tps[ch * ROWU + off + 4]) = o1;
        }
    }
    __syncthreads();
    const bf16x8* w2v = (const bf16x8*)w2p;
#pragma unroll
    for (int mf = 0; mf < 4; ++mf)
#pragma unroll
        for (int nf = 0; nf < 4; ++nf) acc[mf][nf] = (f32x4){0.f, 0.f, 0.f, 0.f};
#pragma unroll
    for (int ks = 0; ks < 2; ++ks) {
        int kb = ks * 32 + lg * 8;
        bf16x8 afr[4];
#pragma unroll
        for (int mf = 0; mf < 4; ++mf) {
            int pos = mf * 16 + l15;
            bf16x8 a;
#pragma unroll
            for (int j = 0; j < 8; ++j) a[j] = (short)tps[(kb + j) * ROWU + pos];
            afr[mf] = a;
        }
#pragma unroll
        for (int nf = 0; nf < 4; ++nf) {
            int fi = ks * 16 + (w * 4 + nf);
            bf16x8 bfr = w2v[fi * 64 + lane];
#pragma unroll
            for (int mf = 0; mf < 4; ++mf)
                acc[mf][nf] = __builtin_amdgcn_mfma_f32_16x16x32_bf16(afr[mf], bfr, acc[mf][nf], 0, 0, 0);
        }
    }
}

// ---------------------------------------------------------------------------
// K6a: conv2 STATS pass — GEMM, bias, GN2 sum/ssq atomics; NO raw store
// ---------------------------------------------------------------------------
__global__ __launch_bounds__(256) void k_conv2s(const unsigned short* __restrict__ t,
        const float* __restrict__ gnsa, const float* __restrict__ gsw,
        const float* __restrict__ gsb, const unsigned short* __restrict__ w2p,
        const float* __restrict__ b2, float* __restrict__ gn2a) {
    int bid = blockIdx.x;
    int b = bid >> 8, pt = bid & 255;
    int p0 = pt * 64;
    int tid = threadIdx.x;
    int w = tid >> 6, lane = tid & 63;
    int l15 = lane & 15, lg = lane >> 4;
    __shared__ float lsc[64], lsh[64];
    __shared__ unsigned short tps[64 * ROWU];
    __shared__ float red[4][4][2];
    f32x4 acc[4][4];
    conv2_panel(t, gnsa, gsw, gsb, w2p, b, p0, tid, w, lane, l15, lg, lsc, lsh, tps, acc);
    float sred[4], ssred[4];
#pragma unroll
    for (int nf = 0; nf < 4; ++nf) {
        int oc = w * 64 + nf * 16 + l15;
        float bias = b2[oc];
        float s = 0.f, ss = 0.f;
#pragma unroll
        for (int mf = 0; mf < 4; ++mf) {
            f32x4 v = acc[mf][nf];
            v[0] += bias; v[1] += bias; v[2] += bias; v[3] += bias;
            s += v[0] + v[1] + v[2] + v[3];
            ss += v[0] * v[0] + v[1] * v[1] + v[2] * v[2] + v[3] * v[3];
        }
#pragma unroll
        for (int off = 32; off; off >>= 1) { s += __shfl_xor(s, off, 64); ss += __shfl_xor(ss, off, 64); }
        sred[nf] = s; ssred[nf] = ss;
    }
    if (lane == 0) {
#pragma unroll
        for (int nf = 0; nf < 4; ++nf) { red[w][nf][0] = sred[nf]; red[w][nf][1] = ssred[nf]; }
    }
    __syncthreads();
    if (tid < 32) {
        int w_ = tid >> 3, nf = (tid >> 1) & 3, c = tid & 1;
        int g = w_ * 4 + nf;
        atomicAdd(&gn2a[(b * 16 + g) * 2 + c], red[w_][nf][c]);
    }
}

// ---------------------------------------------------------------------------
// K6b: fused FINAL — recompute conv2 GEMM, bias, GN2 affine, relu, +x -> out
// ---------------------------------------------------------------------------
__global__ __launch_bounds__(256) void k_final(const unsigned short* __restrict__ t,
        const float* __restrict__ gnsa, const float* __restrict__ gsw,
        const float* __restrict__ gsb, const unsigned short* __restrict__ w2p,
        const float* __restrict__ b2, const float* __restrict__ gn2a,
        const float* __restrict__ g2w, const float* __restrict__ g2b,
        const float* __restrict__ x, float* __restrict__ out) {
    int bid = blockIdx.x;
    int b = bid >> 8, pt = bid & 255;
    int p0 = pt * 64;
    int tid = threadIdx.x;
    int w = tid >> 6, lane = tid & 63;
    int l15 = lane & 15, lg = lane >> 4;
    __shared__ float lsc[64], lsh[64];
    __shared__ unsigned short tps[64 * ROWU];
    f32x4 acc[4][4];
    conv2_panel(t, gnsa, gsw, gsb, w2p, b, p0, tid, w, lane, l15, lg, lsc, lsh, tps, acc);
    const float* xb = x + b * CHW;
    float* ob = out + b * CHW;
#pragma unroll
    for (int nf = 0; nf < 4; ++nf) {
        int oc = w * 64 + nf * 16 + l15;
        float bias = b2[oc];
        float s2, h2;
        gn_affine(gn2a, b, oc >> 4, 1.f / 262144.f, g2w, g2b, oc, s2, h2);
#pragma unroll
        for (int mf = 0; mf < 4; ++mf) {
            int off = oc * HW + p0 + mf * 16 + lg * 4;
            f32x4 xv = __builtin_nontemporal_load((const f32x4*)(xb + off));
            f32x4 v = acc[mf][nf];
            f32x4 r;
            r[0] = fmaxf(fmaf(v[0] + bias, s2, h2), 0.f) + xv[0];
            r[1] = fmaxf(fmaf(v[1] + bias, s2, h2), 0.f) + xv[1];
            r[2] = fmaxf(fmaf(v[2] + bias, s2, h2), 0.f) + xv[2];
            r[3] = fmaxf(fmaf(v[3] + bias, s2, h2), 0.f) + xv[3];
            __builtin_nontemporal_store(r, (f32x4*)(ob + off));
        }
    }
}

// ---------------------------------------------------------------------------
extern "C" void kernel_launch(void* const* d_in, const int* in_sizes, int n_in,
                              void* d_out, int out_size, void* d_ws, size_t ws_size,
                              hipStream_t stream) {
    (void)in_sizes; (void)n_in; (void)out_size; (void)ws_size;
    const float* x   = (const float*)d_in[0];
    const float* W1  = (const float*)d_in[1];
    const float* W2  = (const float*)d_in[2];
    const float* c1w = (const float*)d_in[3];
    const float* c1b = (const float*)d_in[4];
    const float* c2w = (const float*)d_in[5];
    const float* c2b = (const float*)d_in[6];
    const float* g1w = (const float*)d_in[7];
    const float* g1b = (const float*)d_in[8];
    const float* gsw = (const float*)d_in[9];
    const float* gsb = (const float*)d_in[10];
    const float* g2w = (const float*)d_in[11];
    const float* g2b = (const float*)d_in[12];
    float* out = (float*)d_out;
    float* ws  = (float*)d_ws;

    unsigned short* tb   = (unsigned short*)(ws + WS_TB);
    unsigned short* h1b  = (unsigned short*)(ws + WS_H1B);
    float* w2e  = ws + WS_W2E;
    float* k1e  = ws + WS_K1E;
    float* gn1a = ws + WS_GN1A;
    float* gnsa = ws + WS_GNSA;
    float* gn2a = ws + WS_GN2A;
    unsigned short* w1p = (unsigned short*)(ws + WS_W1P);
    unsigned short* w2p = (unsigned short*)(ws + WS_W2P);

    k_setup<<<1, 128, 0, stream>>>(W1, W2, c1w, c2w, k1e, w2e, gn1a, w1p, w2p);
    k_conv1<<<1024, 256, 0, stream>>>(x, w1p, c1b, h1b, gn1a);
    k_x3<<<512, 256, 0, stream>>>(h1b, gn1a, g1w, g1b, k1e, tb);
    k_xsa<<<4096, 256, 0, stream>>>(h1b, gn1a, g1w, g1b, w2e, tb, gnsa);
    k_conv2s<<<4096, 256, 0, stream>>>(tb, gnsa, gsw, gsb, w2p, c2b, gn2a);
    k_final<<<4096, 256, 0, stream>>>(tb, gnsa, gsw, gsb, w2p, c2b, gn2a, g2w, g2b, x, out);
}